// Round 1
// baseline (361.524 us; speedup 1.0000x reference)
//
#include <hip/hip_runtime.h>
#include <hip/hip_bf16.h>

// ---------------------------------------------------------------------------
// Problem: B=2, L=64, H=W=64.
//   h = conv3x3(relu(conv3x3(x,w1,b1)), w2, b2)
//   t = tokens of h  [B, HW, 64]
//   q = l2norm(t@wq^T); k = l2norm(t@wk^T); v = t@wv^T
//   out_c = sum_d softmax_d(q_c * k_d) * v_d   (per token)
//   y = out@wo^T + bo + h
// ---------------------------------------------------------------------------

#define IMG 262144  // 64*64*64 elements per batch image

// ---------------- direct 3x3 conv, 64->64 ch, pad 1 ------------------------
// 1 thread per output element. Lanes vary x -> coalesced input loads; oc is
// wave-uniform -> weight reads become scalar loads.
template <bool RELU>
__global__ __launch_bounds__(256) void conv3x3_k(
    const float* __restrict__ in, const float* __restrict__ w,
    const float* __restrict__ bias, float* __restrict__ out)
{
    int idx = blockIdx.x * 256 + threadIdx.x;
    int x  = idx & 63;
    int y  = (idx >> 6) & 63;
    int oc = (idx >> 12) & 63;
    int b  = idx >> 18;

    const float* inb  = in + b * IMG + y * 64 + x;
    const float* wrow = w + oc * 576;

    float acc = bias[oc];
    for (int ic = 0; ic < 64; ++ic) {
        const float* ip = inb + ic * 4096;
        const float* wp = wrow + ic * 9;
        #pragma unroll
        for (int ky = 0; ky < 3; ++ky) {
            int yy = y + ky - 1;
            if (yy < 0 || yy > 63) continue;        // wave-uniform branch
            const float* r = ip + (ky - 1) * 64;
            float w0 = wp[ky * 3 + 0];
            float w1 = wp[ky * 3 + 1];
            float w2 = wp[ky * 3 + 2];
            acc = fmaf(r[0], w1, acc);
            if (x > 0)  acc = fmaf(r[-1], w0, acc);
            if (x < 63) acc = fmaf(r[1],  w2, acc);
        }
    }
    if (RELU) acc = fmaxf(acc, 0.f);
    out[idx] = acc;
}

// round-to-nearest-even float -> bf16 bits
static __device__ inline unsigned f2bf(float f) {
    unsigned u = __float_as_uint(f);
    return (u + 0x7FFFu + ((u >> 16) & 1u)) >> 16;
}

// ---------------- per-token attention + out-proj + residual ----------------
// Block: 256 threads (4 waves), 32 tokens (one half-row y, x0..x0+31).
// Wave w handles tokens 8w..8w+7; lane = channel.
// h is read AND written in place (block-local tile, staged through LDS).
__global__ __launch_bounds__(256) void attn_k(
    const float* __restrict__ wq, const float* __restrict__ wk,
    const float* __restrict__ wv, const float* __restrict__ wo,
    const float* __restrict__ bo, float* __restrict__ h /* in: conv2 out, out: final */)
{
    // token-major h tile, row stride 66 floats (bank-conflict pad, float2-aligned)
    __shared__ float t_lds[32 * 66];
    // weights as packed bf16 pairs: [c][dp] pair = (w[c][2dp], w[c][2dp+1])
    // row stride 33 uints -> bank (c + dp) % 32: conflict-free for lane=c reads
    __shared__ unsigned wq_l[64 * 33], wk_l[64 * 33], wv_l[64 * 33], wo_l[64 * 33];

    const int tid = threadIdx.x;
    const int bb  = blockIdx.x >> 7;          // batch
    const int y   = (blockIdx.x >> 1) & 63;   // row
    const int x0  = (blockIdx.x & 1) * 32;    // half-row offset
    float* hb = h + bb * IMG + y * 64 + x0;

    // ---- stage h tile: 64 ch x 32 x (coalesced 32-lane reads) ----
    #pragma unroll
    for (int j = 0; j < 8; ++j) {
        int c = j * 8 + (tid >> 5);
        int x = tid & 31;
        t_lds[x * 66 + c] = hb[c * 4096 + x];
    }
    // ---- stage weights, fp32 -> packed bf16 (coalesced float2 reads) ----
    const float2* wq2 = (const float2*)wq;
    const float2* wk2 = (const float2*)wk;
    const float2* wv2 = (const float2*)wv;
    const float2* wo2 = (const float2*)wo;
    #pragma unroll
    for (int j = 0; j < 8; ++j) {
        int p  = j * 256 + tid;        // pair index 0..2047
        int c  = p >> 5;
        int dp = p & 31;
        int a  = c * 33 + dp;
        float2 vq = wq2[p];  wq_l[a] = f2bf(vq.x) | (f2bf(vq.y) << 16);
        float2 vk = wk2[p];  wk_l[a] = f2bf(vk.x) | (f2bf(vk.y) << 16);
        float2 vv = wv2[p];  wv_l[a] = f2bf(vv.x) | (f2bf(vv.y) << 16);
        float2 vo = wo2[p];  wo_l[a] = f2bf(vo.x) | (f2bf(vo.y) << 16);
    }
    __syncthreads();

    const int wave = tid >> 6;
    const int lane = tid & 63;
    const float bo_c = bo[lane];
    const int wbase = lane * 33;

    for (int it = 0; it < 8; ++it) {
        const int tok = wave * 8 + it;
        const float* trow = &t_lds[tok * 66];

        // ---- q,k,v matvecs: lane c accumulates row c dot t ----
        float qc = 0.f, kc = 0.f, vc = 0.f;
        #pragma unroll 8
        for (int dp = 0; dp < 32; ++dp) {
            float2 tv = *(const float2*)(trow + 2 * dp);   // broadcast (free)
            unsigned pq = wq_l[wbase + dp];
            unsigned pk = wk_l[wbase + dp];
            unsigned pv = wv_l[wbase + dp];
            qc = fmaf(__uint_as_float(pq << 16),          tv.x, qc);
            qc = fmaf(__uint_as_float(pq & 0xFFFF0000u),  tv.y, qc);
            kc = fmaf(__uint_as_float(pk << 16),          tv.x, kc);
            kc = fmaf(__uint_as_float(pk & 0xFFFF0000u),  tv.y, kc);
            vc = fmaf(__uint_as_float(pv << 16),          tv.x, vc);
            vc = fmaf(__uint_as_float(pv & 0xFFFF0000u),  tv.y, vc);
        }

        // ---- L2 norms via wave butterfly ----
        float nq = qc * qc, nk = kc * kc;
        #pragma unroll
        for (int s = 32; s > 0; s >>= 1) {
            nq += __shfl_xor(nq, s);
            nk += __shfl_xor(nk, s);
        }
        qc /= fmaxf(sqrtf(nq), 1e-12f);
        kc /= fmaxf(sqrtf(nk), 1e-12f);

        // ---- attention: scores in [-1,1], no max-sub needed ----
        float den = 0.f, num = 0.f;
        #pragma unroll 8
        for (int d = 0; d < 64; ++d) {
            float kd = __shfl(kc, d);
            float vd = __shfl(vc, d);
            float e  = __expf(qc * kd);
            den += e;
            num = fmaf(e, vd, num);
        }
        float oc_ = num / den;

        // ---- output projection + bias + residual ----
        float res = trow[lane];
        float o2 = bo_c;
        #pragma unroll 8
        for (int dp = 0; dp < 32; ++dp) {
            unsigned pw = wo_l[wbase + dp];
            float od0 = __shfl(oc_, 2 * dp);
            float od1 = __shfl(oc_, 2 * dp + 1);
            o2 = fmaf(__uint_as_float(pw << 16),         od0, o2);
            o2 = fmaf(__uint_as_float(pw & 0xFFFF0000u), od1, o2);
        }

        // overwrite own token row (only this wave touches row `tok`)
        t_lds[tok * 66 + lane] = o2 + res;
    }
    __syncthreads();

    // ---- coalesced store back ----
    #pragma unroll
    for (int j = 0; j < 8; ++j) {
        int c = j * 8 + (tid >> 5);
        int x = tid & 31;
        hb[c * 4096 + x] = t_lds[x * 66 + c];
    }
}

extern "C" void kernel_launch(void* const* d_in, const int* in_sizes, int n_in,
                              void* d_out, int out_size, void* d_ws, size_t ws_size,
                              hipStream_t stream) {
    const float* x  = (const float*)d_in[0];
    const float* w1 = (const float*)d_in[1];
    const float* b1 = (const float*)d_in[2];
    const float* w2 = (const float*)d_in[3];
    const float* b2 = (const float*)d_in[4];
    const float* wq = (const float*)d_in[5];
    const float* wk = (const float*)d_in[6];
    const float* wv = (const float*)d_in[7];
    const float* wo = (const float*)d_in[8];
    const float* bo = (const float*)d_in[9];
    float* out = (float*)d_out;
    float* h1  = (float*)d_ws;   // 2 MB scratch for conv1 output

    // conv1 + relu -> ws
    conv3x3_k<true ><<<2048, 256, 0, stream>>>(x, w1, b1, h1);
    // conv2 -> d_out (holds h)
    conv3x3_k<false><<<2048, 256, 0, stream>>>(h1, w2, b2, out);
    // attention + out-proj + residual, in place on d_out
    attn_k<<<256, 256, 0, stream>>>(wq, wk, wv, wo, bo, out);
}

// Round 2
// 136.153 us; speedup vs baseline: 2.6553x; 2.6553x over previous
//
#include <hip/hip_runtime.h>
#include <hip/hip_bf16.h>

// ---------------------------------------------------------------------------
// B=2, L=64, H=W=64.
//   h = conv3x3(relu(conv3x3(x,w1,b1)), w2, b2)          [MFMA bf16 implicit GEMM]
//   per-token rank-1 attention + out-proj + residual      [wave-per-2-tokens]
// ---------------------------------------------------------------------------

#define IMG 262144   // 64*64*64 elements per batch image

using frag_ab = __attribute__((ext_vector_type(8))) short;  // 8 bf16
using frag_cd = __attribute__((ext_vector_type(4))) float;  // 4 fp32

// round-to-nearest-even float -> bf16 bits
static __device__ inline unsigned short f2bf(float f) {
    unsigned u = __float_as_uint(f);
    return (unsigned short)((u + 0x7FFFu + ((u >> 16) & 1u)) >> 16);
}
static __device__ inline float bflo(unsigned p) { return __uint_as_float(p << 16); }
static __device__ inline float bfhi(unsigned p) { return __uint_as_float(p & 0xFFFF0000u); }

// ---------------- prep: transpose conv weights to bf16 [tap][oc][ic] --------
__global__ __launch_bounds__(256) void prep_w(
    const float* __restrict__ w1, const float* __restrict__ w2,
    unsigned short* __restrict__ wt1, unsigned short* __restrict__ wt2)
{
    int i = blockIdx.x * 256 + threadIdx.x;   // 0..73727
    int mat = i >= 36864;
    int j = i - mat * 36864;
    int tap = j >> 12;          // 0..8
    int oc  = (j >> 6) & 63;
    int ic  = j & 63;
    const float* w = mat ? w2 : w1;
    float v = w[(oc * 64 + ic) * 9 + tap];
    (mat ? wt2 : wt1)[j] = f2bf(v);
}

// ---------------- conv3x3 via MFMA: one block per (batch,row) ---------------
// Block = 256 thr = 4 waves; wave w computes oc [16w,16w+16) x 64 x.
// LDS tile: 3 rows x 66 xslots (x=-1..64, zero halo) x 64 ic bf16, xslot
// stride 72 (144B) -> 16B-aligned ds_read_b128, uniform bank spread.
template <bool IN_BF16, bool OUT_BF16, bool RELU>
__global__ __launch_bounds__(256) void conv_mfma(
    const void* __restrict__ inv, const unsigned short* __restrict__ wt,
    const float* __restrict__ bias, void* __restrict__ outv)
{
    __shared__ __align__(16) unsigned short tile[3 * 66 * 72];

    const int tid  = threadIdx.x;
    const int b    = blockIdx.x >> 6;
    const int y    = blockIdx.x & 63;
    const int wv   = tid >> 6;
    const int lane = tid & 63;
    const int m    = lane & 15;   // A: oc offset; B: x offset; D: col
    const int q    = lane >> 4;   // k-chunk selector
    const int oc0  = wv * 16;

    // ---- A-fragments (weights) into registers: 9 taps x 2 ksteps ----
    frag_ab A[9][2];
    #pragma unroll
    for (int t = 0; t < 9; ++t)
        #pragma unroll
        for (int s = 0; s < 2; ++s)
            A[t][s] = *(const frag_ab*)&wt[(t * 64 + oc0 + m) * 64 + s * 32 + q * 8];

    // ---- stage input tile: 192 (row,ic) pairs x 64 x ----
    {
        int xx  = lane;        // within-wave lane = x (coalesced global)
        int sub = wv;          // wave-uniform pair selector
        #pragma unroll
        for (int it = 0; it < 48; ++it) {
            int pair = it * 4 + sub;           // 0..191
            int row = pair >> 6, ic = pair & 63;
            int yy = y + row - 1;
            unsigned short val = 0;
            if (yy >= 0 && yy < 64) {
                int gidx = ((b * 64 + ic) * 64 + yy) * 64 + xx;
                if (IN_BF16) val = ((const unsigned short*)inv)[gidx];
                else         val = f2bf(((const float*)inv)[gidx]);
            }
            tile[(row * 66 + xx + 1) * 72 + ic] = val;
        }
        if (tid < 192) {   // zero x halo (xslot 0 and 65); wave 3 skips uniformly
            int row = tid >> 6, ic = tid & 63;
            tile[(row * 66 + 0)  * 72 + ic] = 0;
            tile[(row * 66 + 65) * 72 + ic] = 0;
        }
    }
    __syncthreads();

    // ---- MFMA main: 9 taps x 2 ksteps x 4 N-tiles = 72 mfma/wave ----
    frag_cd acc[4];
    #pragma unroll
    for (int i = 0; i < 4; ++i) acc[i] = (frag_cd){0.f, 0.f, 0.f, 0.f};

    #pragma unroll
    for (int ky = 0; ky < 3; ++ky) {
        #pragma unroll
        for (int kx = 0; kx < 3; ++kx) {
            #pragma unroll
            for (int s = 0; s < 2; ++s) {
                frag_ab a = A[ky * 3 + kx][s];
                const unsigned short* bp =
                    &tile[(ky * 66 + kx + m) * 72 + s * 32 + q * 8];
                #pragma unroll
                for (int nt = 0; nt < 4; ++nt) {
                    frag_ab bfr = *(const frag_ab*)(bp + nt * 16 * 72);
                    acc[nt] = __builtin_amdgcn_mfma_f32_16x16x32_bf16(
                        a, bfr, acc[nt], 0, 0, 0);
                }
            }
        }
    }

    // ---- epilogue: D row = oc0 + q*4 + r, col = x = nt*16 + m ----
    frag_cd bia = *(const frag_cd*)&bias[oc0 + q * 4];
    #pragma unroll
    for (int nt = 0; nt < 4; ++nt) {
        int x = nt * 16 + m;
        #pragma unroll
        for (int r = 0; r < 4; ++r) {
            int oc = oc0 + q * 4 + r;
            float v = acc[nt][r] + bia[r];
            if (RELU) v = fmaxf(v, 0.f);
            int idx = ((b * 64 + oc) * 64 + y) * 64 + x;
            if (OUT_BF16) ((unsigned short*)outv)[idx] = f2bf(v);
            else          ((float*)outv)[idx] = v;
        }
    }
}

// ---------------- per-token attention + out-proj + residual -----------------
// Grid 1024: 8 tokens/block, 4 waves, 2 tokens/wave (register-interleaved).
__global__ __launch_bounds__(256) void attn_k(
    const float* __restrict__ wq, const float* __restrict__ wk,
    const float* __restrict__ wv, const float* __restrict__ wo,
    const float* __restrict__ bo, float* __restrict__ h)
{
    __shared__ float t_lds[8 * 66];
    __shared__ unsigned wq_l[64 * 33], wk_l[64 * 33], wv_l[64 * 33], wo_l[64 * 33];

    const int tid = threadIdx.x;
    const int bb  = blockIdx.x >> 9;            // batch
    const int t0  = (blockIdx.x & 511) * 8;     // token base (spatial index)
    float* hb = h + bb * IMG + t0;              // h[b][c][tok]: c*4096 + tok

    // ---- stage 8-token tile (coalesced float2) ----
    {
        int c  = tid >> 2;
        int xi = (tid & 3) * 2;
        float2 v = *(const float2*)(hb + c * 4096 + xi);
        t_lds[xi * 66 + c]       = v.x;
        t_lds[(xi + 1) * 66 + c] = v.y;
    }
    // ---- stage weights fp32 -> packed bf16 pairs ----
    const float2* wq2 = (const float2*)wq;
    const float2* wk2 = (const float2*)wk;
    const float2* wv2 = (const float2*)wv;
    const float2* wo2 = (const float2*)wo;
    #pragma unroll
    for (int j = 0; j < 8; ++j) {
        int p  = j * 256 + tid;        // pair index 0..2047
        int c  = p >> 5;
        int dp = p & 31;
        int a  = c * 33 + dp;
        float2 vq = wq2[p];  wq_l[a] = f2bf(vq.x) | ((unsigned)f2bf(vq.y) << 16);
        float2 vk = wk2[p];  wk_l[a] = f2bf(vk.x) | ((unsigned)f2bf(vk.y) << 16);
        float2 vv = wv2[p];  wv_l[a] = f2bf(vv.x) | ((unsigned)f2bf(vv.y) << 16);
        float2 vo = wo2[p];  wo_l[a] = f2bf(vo.x) | ((unsigned)f2bf(vo.y) << 16);
    }
    __syncthreads();

    const int wave = tid >> 6;
    const int lane = tid & 63;
    const int ta = wave * 2, tb = ta + 1;
    const float* trA = &t_lds[ta * 66];
    const float* trB = &t_lds[tb * 66];
    const float bo_c = bo[lane];
    const int wbase = lane * 33;

    // ---- q,k,v matvecs, two tokens interleaved ----
    float qa = 0.f, ka = 0.f, va = 0.f, qb = 0.f, kb = 0.f, vb = 0.f;
    #pragma unroll 8
    for (int dp = 0; dp < 32; ++dp) {
        float2 tva = *(const float2*)(trA + 2 * dp);   // broadcast
        float2 tvb = *(const float2*)(trB + 2 * dp);
        unsigned pq = wq_l[wbase + dp];
        unsigned pk = wk_l[wbase + dp];
        unsigned pv = wv_l[wbase + dp];
        qa = fmaf(bflo(pq), tva.x, qa); qa = fmaf(bfhi(pq), tva.y, qa);
        ka = fmaf(bflo(pk), tva.x, ka); ka = fmaf(bfhi(pk), tva.y, ka);
        va = fmaf(bflo(pv), tva.x, va); va = fmaf(bfhi(pv), tva.y, va);
        qb = fmaf(bflo(pq), tvb.x, qb); qb = fmaf(bfhi(pq), tvb.y, qb);
        kb = fmaf(bflo(pk), tvb.x, kb); kb = fmaf(bfhi(pk), tvb.y, kb);
        vb = fmaf(bflo(pv), tvb.x, vb); vb = fmaf(bfhi(pv), tvb.y, vb);
    }

    // ---- L2 norms (wave butterfly) ----
    float nqa = qa * qa, nka = ka * ka, nqb = qb * qb, nkb = kb * kb;
    #pragma unroll
    for (int s = 32; s > 0; s >>= 1) {
        nqa += __shfl_xor(nqa, s);
        nka += __shfl_xor(nka, s);
        nqb += __shfl_xor(nqb, s);
        nkb += __shfl_xor(nkb, s);
    }
    qa /= fmaxf(sqrtf(nqa), 1e-12f);
    ka /= fmaxf(sqrtf(nka), 1e-12f);
    qb /= fmaxf(sqrtf(nqb), 1e-12f);
    kb /= fmaxf(sqrtf(nkb), 1e-12f);

    // ---- softmax attention: scores in [-1,1], no max-sub needed ----
    float dena = 0.f, numa = 0.f, denb = 0.f, numb = 0.f;
    #pragma unroll 16
    for (int d = 0; d < 64; ++d) {
        float kda = __shfl(ka, d), vda = __shfl(va, d);
        float kdb = __shfl(kb, d), vdb = __shfl(vb, d);
        float ea = __expf(qa * kda);
        float eb = __expf(qb * kdb);
        dena += ea; numa = fmaf(ea, vda, numa);
        denb += eb; numb = fmaf(eb, vdb, numb);
    }
    float oa = numa / dena, ob = numb / denb;

    // ---- output projection + bias + residual ----
    float ra = trA[lane], rb = trB[lane];
    float oa2 = bo_c, ob2 = bo_c;
    #pragma unroll 8
    for (int dp = 0; dp < 32; ++dp) {
        unsigned pw = wo_l[wbase + dp];
        float w0 = bflo(pw), w1 = bfhi(pw);
        float da0 = __shfl(oa, 2 * dp), da1 = __shfl(oa, 2 * dp + 1);
        float db0 = __shfl(ob, 2 * dp), db1 = __shfl(ob, 2 * dp + 1);
        oa2 = fmaf(w0, da0, oa2); oa2 = fmaf(w1, da1, oa2);
        ob2 = fmaf(w0, db0, ob2); ob2 = fmaf(w1, db1, ob2);
    }
    t_lds[ta * 66 + lane] = oa2 + ra;
    t_lds[tb * 66 + lane] = ob2 + rb;
    __syncthreads();

    // ---- coalesced store back ----
    {
        int c  = tid >> 2;
        int xi = (tid & 3) * 2;
        float2 o;
        o.x = t_lds[xi * 66 + c];
        o.y = t_lds[(xi + 1) * 66 + c];
        *(float2*)(hb + c * 4096 + xi) = o;
    }
}

extern "C" void kernel_launch(void* const* d_in, const int* in_sizes, int n_in,
                              void* d_out, int out_size, void* d_ws, size_t ws_size,
                              hipStream_t stream) {
    const float* x  = (const float*)d_in[0];
    const float* w1 = (const float*)d_in[1];
    const float* b1 = (const float*)d_in[2];
    const float* w2 = (const float*)d_in[3];
    const float* b2 = (const float*)d_in[4];
    const float* wq = (const float*)d_in[5];
    const float* wk = (const float*)d_in[6];
    const float* wv = (const float*)d_in[7];
    const float* wo = (const float*)d_in[8];
    const float* bo = (const float*)d_in[9];
    float* out = (float*)d_out;

    // ws layout: h1 bf16 [2*64*64*64] then wt1, wt2 bf16 [9*64*64] each
    unsigned short* h1  = (unsigned short*)d_ws;            // 1 MB
    unsigned short* wt1 = h1 + 524288;                      // 16B-aligned
    unsigned short* wt2 = wt1 + 36864;

    prep_w<<<288, 256, 0, stream>>>(w1, w2, wt1, wt2);
    // conv1 + relu -> bf16 h1 (ws)
    conv_mfma<false, true, true ><<<128, 256, 0, stream>>>(x, wt1, b1, h1);
    // conv2 -> fp32 h (d_out)
    conv_mfma<true, false, false><<<128, 256, 0, stream>>>(h1, wt2, b2, out);
    // attention + out-proj + residual, in place on d_out
    attn_k<<<1024, 256, 0, stream>>>(wq, wk, wv, wo, bo, out);
}

// Round 3
// 111.511 us; speedup vs baseline: 3.2421x; 1.2210x over previous
//
#include <hip/hip_runtime.h>
#include <hip/hip_bf16.h>

// ---------------------------------------------------------------------------
// B=2, L=64, H=W=64.
//   h = conv3x3(relu(conv3x3(x,w1,b1)), w2, b2)       [MFMA bf16 implicit GEMM]
//   per-token rank-1 attention + out-proj + residual  [wave-per-2-tokens]
// ---------------------------------------------------------------------------

#define IMG 262144   // 64*64*64 elements per batch image

using frag_ab = __attribute__((ext_vector_type(8))) short;  // 8 bf16
using frag_cd = __attribute__((ext_vector_type(4))) float;  // 4 fp32

// round-to-nearest-even float -> bf16 bits
static __device__ inline unsigned short f2bf(float f) {
    unsigned u = __float_as_uint(f);
    return (unsigned short)((u + 0x7FFFu + ((u >> 16) & 1u)) >> 16);
}
static __device__ inline float bflo(unsigned p) { return __uint_as_float(p << 16); }
static __device__ inline float bfhi(unsigned p) { return __uint_as_float(p & 0xFFFF0000u); }

// ---------------- prep: conv wts -> bf16 [tap][oc][ic]; attn wts -> packed --
__global__ __launch_bounds__(256) void prep_w(
    const float* __restrict__ w1, const float* __restrict__ w2,
    const float* __restrict__ wq, const float* __restrict__ wk,
    const float* __restrict__ wv, const float* __restrict__ wo,
    unsigned short* __restrict__ wt1, unsigned short* __restrict__ wt2,
    unsigned* __restrict__ wp)
{
    int i = blockIdx.x * 256 + threadIdx.x;
    if (i < 73728) {
        int mat = i >= 36864;
        int j = i - mat * 36864;
        int tap = j >> 12;          // 0..8
        int oc  = (j >> 6) & 63;
        int ic  = j & 63;
        const float* w = mat ? w2 : w1;
        (mat ? wt2 : wt1)[j] = f2bf(w[(oc * 64 + ic) * 9 + tap]);
    } else if (i < 73728 + 8192) {
        // attn weights: wp[mat*2048 + dp*64 + c] = pack(w[c][2dp], w[c][2dp+1])
        int a = i - 73728;
        int mat = a >> 11;
        int r = a & 2047;
        int dp = r >> 6, c = r & 63;
        const float* w = (mat == 0) ? wq : (mat == 1) ? wk : (mat == 2) ? wv : wo;
        wp[a] = (unsigned)f2bf(w[c * 64 + 2 * dp]) |
                ((unsigned)f2bf(w[c * 64 + 2 * dp + 1]) << 16);
    }
}

// ---------------- conv3x3 via MFMA: one block per (batch,row,xhalf) --------
// Grid 256. Block = 4 waves; wave w computes oc [16w,16w+16) x 32 x.
// LDS tile: 3 rows x 34 xslots (x0-1 .. x0+32) x 64 ic bf16, xslot stride 72.
// Staging is BRANCH-FREE (clamp + select) so all loads pipeline.
template <bool IN_BF16, bool OUT_BF16, bool RELU>
__global__ __launch_bounds__(256) void conv_mfma(
    const void* __restrict__ inv, const unsigned short* __restrict__ wt,
    const float* __restrict__ bias, void* __restrict__ outv)
{
    __shared__ __align__(16) unsigned short tile[3 * 34 * 72];   // 14.7 KB

    const int tid  = threadIdx.x;
    const int b    = blockIdx.x >> 7;
    const int y    = (blockIdx.x >> 1) & 63;
    const int x0   = (blockIdx.x & 1) * 32;
    const int wv   = tid >> 6;
    const int lane = tid & 63;
    const int m    = lane & 15;   // A: oc offset; B: x offset; D: col
    const int q    = lane >> 4;   // k-chunk selector
    const int oc0  = wv * 16;

    // ---- A-fragments (weights) into registers: 9 taps x 2 ksteps ----
    frag_ab A[9][2];
    #pragma unroll
    for (int t = 0; t < 9; ++t)
        #pragma unroll
        for (int s = 0; s < 2; ++s)
            A[t][s] = *(const frag_ab*)&wt[(t * 64 + oc0 + m) * 64 + s * 32 + q * 8];

    // ---- stage input tile, branch-free ----
    {
        const int xl  = tid & 31;
        const int sub = tid >> 5;        // 0..7
        #pragma unroll
        for (int i = 0; i < 24; ++i) {
            int pair = i * 8 + sub;       // 0..191
            int row = pair >> 6, ic = pair & 63;
            int yy = y + row - 1;
            int yc = min(max(yy, 0), 63);
            int gidx = ((b * 64 + ic) * 64 + yc) * 64 + x0 + xl;
            unsigned short val;
            if (IN_BF16) val = ((const unsigned short*)inv)[gidx];
            else         val = f2bf(((const float*)inv)[gidx]);
            if (yy != yc) val = 0;
            tile[(row * 34 + xl + 1) * 72 + ic] = val;
        }
        if (tid < 192) {   // halo columns (waves 0-2; wave 3 skips uniformly)
            int row = tid >> 6, ic = tid & 63;
            int yy = y + row - 1;
            int yc = min(max(yy, 0), 63);
            bool yok = (yy == yc);
            int xL = x0 - 1, xR = x0 + 32;
            int gbase = ((b * 64 + ic) * 64 + yc) * 64;
            unsigned short vl, vr;
            if (IN_BF16) {
                vl = ((const unsigned short*)inv)[gbase + max(xL, 0)];
                vr = ((const unsigned short*)inv)[gbase + min(xR, 63)];
            } else {
                vl = f2bf(((const float*)inv)[gbase + max(xL, 0)]);
                vr = f2bf(((const float*)inv)[gbase + min(xR, 63)]);
            }
            if (!yok || xL < 0)  vl = 0;
            if (!yok || xR > 63) vr = 0;
            tile[(row * 34 + 0)  * 72 + ic] = vl;
            tile[(row * 34 + 33) * 72 + ic] = vr;
        }
    }
    __syncthreads();

    // ---- MFMA main: 9 taps x 2 ksteps x 2 N-tiles = 36 mfma/wave ----
    frag_cd acc[2];
    acc[0] = (frag_cd){0.f, 0.f, 0.f, 0.f};
    acc[1] = (frag_cd){0.f, 0.f, 0.f, 0.f};

    #pragma unroll
    for (int ky = 0; ky < 3; ++ky) {
        #pragma unroll
        for (int kx = 0; kx < 3; ++kx) {
            #pragma unroll
            for (int s = 0; s < 2; ++s) {
                frag_ab a = A[ky * 3 + kx][s];
                #pragma unroll
                for (int nt = 0; nt < 2; ++nt) {
                    const unsigned short* bp =
                        &tile[(ky * 34 + nt * 16 + m + kx) * 72 + s * 32 + q * 8];
                    acc[nt] = __builtin_amdgcn_mfma_f32_16x16x32_bf16(
                        a, *(const frag_ab*)bp, acc[nt], 0, 0, 0);
                }
            }
        }
    }

    // ---- epilogue: D row = oc0 + q*4 + r, col = x = x0 + nt*16 + m ----
    frag_cd bia = *(const frag_cd*)&bias[oc0 + q * 4];
    #pragma unroll
    for (int nt = 0; nt < 2; ++nt) {
        int x = x0 + nt * 16 + m;
        #pragma unroll
        for (int r = 0; r < 4; ++r) {
            int oc = oc0 + q * 4 + r;
            float v = acc[nt][r] + bia[r];
            if (RELU) v = fmaxf(v, 0.f);
            int idx = ((b * 64 + oc) * 64 + y) * 64 + x;
            if (OUT_BF16) ((unsigned short*)outv)[idx] = f2bf(v);
            else          ((float*)outv)[idx] = v;
        }
    }
}

// ---------------- per-token attention + out-proj + residual -----------------
// Grid 1024: 8 tokens/block, 4 waves, 2 tokens/wave (register-interleaved).
// Weights pre-packed [mat][dp][c] -> linear uint4 LDS copy, no conversion.
__global__ __launch_bounds__(256) void attn_k(
    const unsigned* __restrict__ wp, const float* __restrict__ bo,
    float* __restrict__ h)
{
    __shared__ __align__(16) unsigned w_lds[8192];   // 32 KB
    __shared__ float t_lds[8 * 66];

    const int tid = threadIdx.x;
    const int bb  = blockIdx.x >> 9;            // batch
    const int t0  = (blockIdx.x & 511) * 8;     // token base
    float* hb = h + bb * IMG + t0;              // h[b][c][tok]: c*4096 + tok

    // ---- stage weights: pure linear copy, 8 x uint4 per thread ----
    {
        const uint4* src = (const uint4*)wp;
        uint4* dst = (uint4*)w_lds;
        #pragma unroll
        for (int j = 0; j < 8; ++j) {
            int idx = j * 256 + tid;
            dst[idx] = src[idx];
        }
    }
    // ---- stage 8-token tile (coalesced float2) ----
    {
        int c  = tid >> 2;
        int xi = (tid & 3) * 2;
        float2 v = *(const float2*)(hb + c * 4096 + xi);
        t_lds[xi * 66 + c]       = v.x;
        t_lds[(xi + 1) * 66 + c] = v.y;
    }
    __syncthreads();

    const int wave = tid >> 6;
    const int lane = tid & 63;
    const int ta = wave * 2, tb = ta + 1;
    const float* trA = &t_lds[ta * 66];
    const float* trB = &t_lds[tb * 66];
    const float bo_c = bo[lane];

    // ---- q,k,v matvecs, two tokens interleaved ----
    float qa = 0.f, ka = 0.f, va = 0.f, qb = 0.f, kb = 0.f, vb = 0.f;
    #pragma unroll 8
    for (int dp = 0; dp < 32; ++dp) {
        float2 tva = *(const float2*)(trA + 2 * dp);   // broadcast (free)
        float2 tvb = *(const float2*)(trB + 2 * dp);
        unsigned pq = w_lds[dp * 64 + lane];           // bank = lane%32: free
        unsigned pk = w_lds[2048 + dp * 64 + lane];
        unsigned pv = w_lds[4096 + dp * 64 + lane];
        qa = fmaf(bflo(pq), tva.x, qa); qa = fmaf(bfhi(pq), tva.y, qa);
        ka = fmaf(bflo(pk), tva.x, ka); ka = fmaf(bfhi(pk), tva.y, ka);
        va = fmaf(bflo(pv), tva.x, va); va = fmaf(bfhi(pv), tva.y, va);
        qb = fmaf(bflo(pq), tvb.x, qb); qb = fmaf(bfhi(pq), tvb.y, qb);
        kb = fmaf(bflo(pk), tvb.x, kb); kb = fmaf(bfhi(pk), tvb.y, kb);
        vb = fmaf(bflo(pv), tvb.x, vb); vb = fmaf(bfhi(pv), tvb.y, vb);
    }

    // ---- L2 norms (wave butterfly) ----
    float nqa = qa * qa, nka = ka * ka, nqb = qb * qb, nkb = kb * kb;
    #pragma unroll
    for (int s = 32; s > 0; s >>= 1) {
        nqa += __shfl_xor(nqa, s);
        nka += __shfl_xor(nka, s);
        nqb += __shfl_xor(nqb, s);
        nkb += __shfl_xor(nkb, s);
    }
    qa /= fmaxf(sqrtf(nqa), 1e-12f);
    ka /= fmaxf(sqrtf(nka), 1e-12f);
    qb /= fmaxf(sqrtf(nqb), 1e-12f);
    kb /= fmaxf(sqrtf(nkb), 1e-12f);

    // ---- softmax attention: scores in [-1,1], no max-sub needed ----
    float dena = 0.f, numa = 0.f, denb = 0.f, numb = 0.f;
    #pragma unroll 16
    for (int d = 0; d < 64; ++d) {
        float kda = __shfl(ka, d), vda = __shfl(va, d);
        float kdb = __shfl(kb, d), vdb = __shfl(vb, d);
        float ea = __expf(qa * kda);
        float eb = __expf(qb * kdb);
        dena += ea; numa = fmaf(ea, vda, numa);
        denb += eb; numb = fmaf(eb, vdb, numb);
    }
    float oa = numa / dena, ob = numb / denb;

    // ---- output projection + bias + residual ----
    float ra = trA[lane], rb = trB[lane];
    float oa2 = bo_c, ob2 = bo_c;
    #pragma unroll 8
    for (int dp = 0; dp < 32; ++dp) {
        unsigned pw = w_lds[6144 + dp * 64 + lane];
        float w0 = bflo(pw), w1 = bfhi(pw);
        float da0 = __shfl(oa, 2 * dp), da1 = __shfl(oa, 2 * dp + 1);
        float db0 = __shfl(ob, 2 * dp), db1 = __shfl(ob, 2 * dp + 1);
        oa2 = fmaf(w0, da0, oa2); oa2 = fmaf(w1, da1, oa2);
        ob2 = fmaf(w0, db0, ob2); ob2 = fmaf(w1, db1, ob2);
    }
    t_lds[ta * 66 + lane] = oa2 + ra;
    t_lds[tb * 66 + lane] = ob2 + rb;
    __syncthreads();

    // ---- coalesced store back ----
    {
        int c  = tid >> 2;
        int xi = (tid & 3) * 2;
        float2 o;
        o.x = t_lds[xi * 66 + c];
        o.y = t_lds[(xi + 1) * 66 + c];
        *(float2*)(hb + c * 4096 + xi) = o;
    }
}

extern "C" void kernel_launch(void* const* d_in, const int* in_sizes, int n_in,
                              void* d_out, int out_size, void* d_ws, size_t ws_size,
                              hipStream_t stream) {
    const float* x  = (const float*)d_in[0];
    const float* w1 = (const float*)d_in[1];
    const float* b1 = (const float*)d_in[2];
    const float* w2 = (const float*)d_in[3];
    const float* b2 = (const float*)d_in[4];
    const float* wq = (const float*)d_in[5];
    const float* wk = (const float*)d_in[6];
    const float* wv = (const float*)d_in[7];
    const float* wo = (const float*)d_in[8];
    const float* bo = (const float*)d_in[9];
    float* out = (float*)d_out;

    // ws layout (16B-aligned): wp uint[8192] | h1 bf16[524288] | wt1 | wt2
    unsigned*       wpp = (unsigned*)d_ws;                    // 32 KB
    unsigned short* h1  = (unsigned short*)((char*)d_ws + 32768);
    unsigned short* wt1 = (unsigned short*)((char*)d_ws + 32768 + 1048576);
    unsigned short* wt2 = wt1 + 36864;

    prep_w<<<320, 256, 0, stream>>>(w1, w2, wq, wk, wv, wo, wt1, wt2, wpp);
    // conv1 + relu -> bf16 h1 (ws)
    conv_mfma<false, true, true ><<<256, 256, 0, stream>>>(x, wt1, b1, h1);
    // conv2 -> fp32 h (d_out)
    conv_mfma<true, false, false><<<256, 256, 0, stream>>>(h1, wt2, b2, out);
    // attention + out-proj + residual, in place on d_out
    attn_k<<<1024, 256, 0, stream>>>(wpp, bo, out);
}

// Round 4
// 96.875 us; speedup vs baseline: 3.7318x; 1.1511x over previous
//
#include <hip/hip_runtime.h>
#include <hip/hip_bf16.h>

// ---------------------------------------------------------------------------
// B=2, L=64, H=W=64. Fully fused:
//   block (b, y, x0=16-strip) computes conv1(3 rows, flat-N MFMA) -> r1 (LDS,
//   bf16) -> conv2 (MFMA) -> h (LDS) -> per-token rank-1 attention + out-proj
//   + residual -> global. h never touches HBM. 2 dispatches total.
// ---------------------------------------------------------------------------

#define IMG 262144

using frag_ab = __attribute__((ext_vector_type(8))) short;  // 8 bf16
using frag_cd = __attribute__((ext_vector_type(4))) float;  // 4 fp32
typedef unsigned u32x4 __attribute__((ext_vector_type(4)));
typedef float    f32x2 __attribute__((ext_vector_type(2)));
typedef float    f32x4 __attribute__((ext_vector_type(4)));

static __device__ inline unsigned short f2bf(float f) {
    unsigned u = __float_as_uint(f);
    return (unsigned short)((u + 0x7FFFu + ((u >> 16) & 1u)) >> 16);
}
static __device__ inline float bflo(unsigned p) { return __uint_as_float(p << 16); }
static __device__ inline float bfhi(unsigned p) { return __uint_as_float(p & 0xFFFF0000u); }

#if __has_builtin(__builtin_amdgcn_fdot2_f32_bf16)
typedef __bf16 bf16x2 __attribute__((ext_vector_type(2)));
static __device__ inline float dot2bf(unsigned a, unsigned b, float c) {
    union U { unsigned u; bf16x2 v; };
    U ua, ub; ua.u = a; ub.u = b;
    return __builtin_amdgcn_fdot2_f32_bf16(ua.v, ub.v, c, false);
}
#else
static __device__ inline float dot2bf(unsigned a, unsigned b, float c) {
    return fmaf(bflo(a), bflo(b), fmaf(bfhi(a), bfhi(b), c));
}
#endif

#if __has_builtin(__builtin_amdgcn_exp2f)
#define EXP2F(x) __builtin_amdgcn_exp2f(x)
#else
#define EXP2F(x) __expf(0.6931471805599453f * (x))
#endif

// ---------------- prep: conv wts -> bf16 [tap][oc][ic]; attn wts packed -----
// attn layout: wp[mat*2048 + c*32 + swz(dp,c)] = pack(w[c][2dp], w[c][2dp+1]),
// chunk-XOR swizzle so per-lane b128 reads tile all 32 banks.
__global__ __launch_bounds__(256) void prep_w(
    const float* __restrict__ w1, const float* __restrict__ w2,
    const float* __restrict__ wq, const float* __restrict__ wk,
    const float* __restrict__ wv, const float* __restrict__ wo,
    unsigned short* __restrict__ wt1, unsigned short* __restrict__ wt2,
    unsigned* __restrict__ wp)
{
    int i = blockIdx.x * 256 + threadIdx.x;
    if (i < 73728) {
        int mat = i >= 36864;
        int j = i - mat * 36864;
        int tap = j >> 12;
        int oc  = (j >> 6) & 63;
        int ic  = j & 63;
        const float* w = mat ? w2 : w1;
        (mat ? wt2 : wt1)[j] = f2bf(w[(oc * 64 + ic) * 9 + tap]);
    } else {
        int a = i - 73728;               // 0..8191
        int mat = a >> 11;
        int r = a & 2047;
        int c = r >> 5, dp = r & 31;
        const float* w = (mat == 0) ? wq : (mat == 1) ? wk : (mat == 2) ? wv : wo;
        unsigned val = (unsigned)f2bf(w[c * 64 + 2 * dp]) |
                       ((unsigned)f2bf(w[c * 64 + 2 * dp + 1]) << 16);
        wp[mat * 2048 + c * 32 + (((dp >> 2) ^ (c & 7)) << 2) + (dp & 3)] = val;
    }
}

// ---------------- fully fused kernel ---------------------------------------
// Grid 512 = 2 b x 64 y x 4 xstrips(16). 4 waves; wave w owns oc [16w,16w+16)
// in conv phases and tokens [4w,4w+4) in attention.
__global__ __launch_bounds__(256, 2) void fused_k(
    const float* __restrict__ x,
    const unsigned short* __restrict__ wt1, const unsigned short* __restrict__ wt2,
    const float* __restrict__ b1, const float* __restrict__ b2,
    const unsigned* __restrict__ wp, const float* __restrict__ bo,
    float* __restrict__ out)
{
    __shared__ __align__(16) unsigned       w_lds[6144];        // wq,wk,wv  24576 B
    __shared__ __align__(16) unsigned short xt[5 * 20 * 72];    // x tile    14400 B
    __shared__ __align__(16) unsigned short r1[54 * 72];        // conv1 out  7776 B
    __shared__ __align__(16) float          t_lds[16 * 66];     // h fp32     4224 B
    __shared__ __align__(16) unsigned       tp[16 * 32];        // h bf16pk   2048 B
    __shared__ __align__(16) f32x2          kv[8 * 64];         // k,v bcast  4096 B
    __shared__ __align__(16) unsigned short o_l[8 * 64];        // attn out   1024 B

    const int tid  = threadIdx.x;
    const int b    = blockIdx.x >> 8;
    const int y    = (blockIdx.x >> 2) & 63;
    const int x0   = (blockIdx.x & 3) * 16;
    const int wv_  = tid >> 6;
    const int lane = tid & 63;
    const int m    = lane & 15;
    const int q    = lane >> 4;
    const int oc0  = wv_ * 16;

    // ---- A-fragments for both convs (global, in flight during staging) ----
    frag_ab A1[9][2], A2[9][2];
    #pragma unroll
    for (int t = 0; t < 9; ++t)
        #pragma unroll
        for (int s = 0; s < 2; ++s) {
            A1[t][s] = *(const frag_ab*)&wt1[(t * 64 + oc0 + m) * 64 + s * 32 + q * 8];
            A2[t][s] = *(const frag_ab*)&wt2[(t * 64 + oc0 + m) * 64 + s * 32 + q * 8];
        }

    // ---- stage attn weights q,k,v (linear u32x4 copy) ----
    #pragma unroll
    for (int j = 0; j < 6; ++j)
        ((u32x4*)w_lds)[j * 256 + tid] = ((const u32x4*)wp)[j * 256 + tid];

    // ---- stage x tile: rows y-2..y+2, xslots 0..19 (gx = x0-2+xslot) ----
    {
        const int xl  = tid & 15;
        const int sub = tid >> 4;
        #pragma unroll
        for (int i = 0; i < 20; ++i) {
            int pair = i * 16 + sub;          // 0..319
            int row = pair >> 6, ic = pair & 63;
            int yy = y - 2 + row;
            int yc = min(max(yy, 0), 63);
            float f = x[((b * 64 + ic) * 64 + yc) * 64 + x0 + xl];
            unsigned short v = f2bf(f);
            if (yy != yc) v = 0;
            xt[(row * 20 + xl + 2) * 72 + ic] = v;
        }
        #pragma unroll
        for (int j = 0; j < 5; ++j) {         // halo columns xslot {0,1,18,19}
            int e = j * 256 + tid;            // 0..1279
            int col = e & 3, pair = e >> 2;
            int row = pair >> 6, ic = pair & 63;
            int xsl = (col < 2) ? col : col + 16;
            int gx = x0 - 2 + xsl;
            int gxc = min(max(gx, 0), 63);
            int yy = y - 2 + row;
            int yc = min(max(yy, 0), 63);
            float f = x[((b * 64 + ic) * 64 + yc) * 64 + gxc];
            unsigned short v = f2bf(f);
            if (yy != yc || gx != gxc) v = 0;
            xt[(row * 20 + xsl) * 72 + ic] = v;
        }
    }
    __syncthreads();

    // ---- conv1: flat N = (row 0..2) x (xs 0..17) = 54, 4 tiles of 16 ----
    int pb[4], rn_[4], xs_[4];
    bool nv[4];
    #pragma unroll
    for (int nt = 0; nt < 4; ++nt) {
        int n  = nt * 16 + m;
        int nc = min(n, 53);
        int rr = nc / 18, xx = nc - rr * 18;
        rn_[nt] = rr; xs_[nt] = xx; nv[nt] = (n < 54);
        pb[nt] = (rr * 20 + xx) * 72 + q * 8;
    }
    frag_cd acc1[4];
    #pragma unroll
    for (int i = 0; i < 4; ++i) acc1[i] = (frag_cd){0.f, 0.f, 0.f, 0.f};

    #pragma unroll
    for (int ky = 0; ky < 3; ++ky)
        #pragma unroll
        for (int kx = 0; kx < 3; ++kx)
            #pragma unroll
            for (int s = 0; s < 2; ++s) {
                frag_ab a = A1[ky * 3 + kx][s];
                int off = (ky * 20 + kx) * 72 + s * 32;
                #pragma unroll
                for (int nt = 0; nt < 4; ++nt)
                    acc1[nt] = __builtin_amdgcn_mfma_f32_16x16x32_bf16(
                        a, *(const frag_ab*)&xt[pb[nt] + off], acc1[nt], 0, 0, 0);
            }

    // ---- r1 = bf16(relu(conv1+b1)), zero at image edges ----
    {
        frag_cd b1f = *(const frag_cd*)&b1[oc0 + q * 4];
        #pragma unroll
        for (int nt = 0; nt < 4; ++nt) {
            if (!nv[nt]) continue;
            int n = nt * 16 + m;
            int gy = y - 1 + rn_[nt];
            int gx = x0 - 1 + xs_[nt];
            bool oob = (gy < 0) | (gy > 63) | (gx < 0) | (gx > 63);
            #pragma unroll
            for (int r = 0; r < 4; ++r) {
                float v = fmaxf(acc1[nt][r] + b1f[r], 0.f);
                r1[n * 72 + oc0 + q * 4 + r] = oob ? (unsigned short)0 : f2bf(v);
            }
        }
    }
    __syncthreads();

    // ---- conv2: 1 N-tile (16 tokens), 18 MFMA/wave ----
    frag_cd acc2 = (frag_cd){0.f, 0.f, 0.f, 0.f};
    #pragma unroll
    for (int ky = 0; ky < 3; ++ky)
        #pragma unroll
        for (int kx = 0; kx < 3; ++kx)
            #pragma unroll
            for (int s = 0; s < 2; ++s)
                acc2 = __builtin_amdgcn_mfma_f32_16x16x32_bf16(
                    A2[ky * 3 + kx][s],
                    *(const frag_ab*)&r1[(ky * 18 + m + kx) * 72 + s * 32 + q * 8],
                    acc2, 0, 0, 0);

    // ---- h -> t_lds (fp32 residual) + tp (bf16 pairs for projections) ----
    {
        frag_cd b2f = *(const frag_cd*)&b2[oc0 + q * 4];
        float hv[4];
        #pragma unroll
        for (int r = 0; r < 4; ++r) {
            hv[r] = acc2[r] + b2f[r];
            t_lds[m * 66 + oc0 + q * 4 + r] = hv[r];
        }
        int dpb = (oc0 >> 1) + q * 2;
        tp[m * 32 + dpb + 0] = (unsigned)f2bf(hv[0]) | ((unsigned)f2bf(hv[1]) << 16);
        tp[m * 32 + dpb + 1] = (unsigned)f2bf(hv[2]) | ((unsigned)f2bf(hv[3]) << 16);
    }
    __syncthreads();

    // ---- attention: wave handles tokens 4w..4w+3, 2 at a time ----
    const float bo_c = bo[lane];
    const int c7 = lane & 7;
    const unsigned* wop = wp + 6144;   // wo stays in global (L1-resident)
    const int ra_ = wv_ * 2, rb_ = ra_ + 1;

    #pragma unroll
    for (int it = 0; it < 2; ++it) {
        const int ta = wv_ * 4 + it * 2, tb = ta + 1;

        // q,k,v matvecs via dot2 (lane = output channel c)
        float qa = 0.f, ka = 0.f, va = 0.f, qb = 0.f, kb = 0.f, vb = 0.f;
        #pragma unroll
        for (int dp4 = 0; dp4 < 8; ++dp4) {
            int chunk = ((dp4 ^ c7) << 2);
            u32x4 pq = *(const u32x4*)&w_lds[lane * 32 + chunk];
            u32x4 pk = *(const u32x4*)&w_lds[2048 + lane * 32 + chunk];
            u32x4 pv = *(const u32x4*)&w_lds[4096 + lane * 32 + chunk];
            u32x4 tpa = *(const u32x4*)&tp[ta * 32 + dp4 * 4];   // uniform bcast
            u32x4 tpb = *(const u32x4*)&tp[tb * 32 + dp4 * 4];
            #pragma unroll
            for (int j = 0; j < 4; ++j) {
                qa = dot2bf(pq[j], tpa[j], qa);
                ka = dot2bf(pk[j], tpa[j], ka);
                va = dot2bf(pv[j], tpa[j], va);
                qb = dot2bf(pq[j], tpb[j], qb);
                kb = dot2bf(pk[j], tpb[j], kb);
                vb = dot2bf(pv[j], tpb[j], vb);
            }
        }

        // L2 norms (wave butterfly); q pre-scaled by log2e for exp2
        float nqa = qa * qa, nka = ka * ka, nqb = qb * qb, nkb = kb * kb;
        #pragma unroll
        for (int s = 32; s > 0; s >>= 1) {
            nqa += __shfl_xor(nqa, s);
            nka += __shfl_xor(nka, s);
            nqb += __shfl_xor(nqb, s);
            nkb += __shfl_xor(nkb, s);
        }
        qa = qa / fmaxf(sqrtf(nqa), 1e-12f) * 1.44269504f;
        ka = ka / fmaxf(sqrtf(nka), 1e-12f);
        qb = qb / fmaxf(sqrtf(nqb), 1e-12f) * 1.44269504f;
        kb = kb / fmaxf(sqrtf(nkb), 1e-12f);

        // broadcast k,v through LDS (wave-local, lgkm-ordered)
        kv[ra_ * 64 + lane] = (f32x2){ka, va};
        kv[rb_ * 64 + lane] = (f32x2){kb, vb};

        // softmax: scores in [-1,1] -> no max subtraction needed
        float dena = 0.f, numa = 0.f, denb = 0.f, numb = 0.f;
        #pragma unroll 8
        for (int d2 = 0; d2 < 32; ++d2) {
            f32x4 A_ = *(const f32x4*)&kv[ra_ * 64 + d2 * 2];   // k0,v0,k1,v1
            f32x4 B_ = *(const f32x4*)&kv[rb_ * 64 + d2 * 2];
            float e0 = EXP2F(qa * A_[0]); dena += e0; numa = fmaf(e0, A_[1], numa);
            float e1 = EXP2F(qa * A_[2]); dena += e1; numa = fmaf(e1, A_[3], numa);
            float e2 = EXP2F(qb * B_[0]); denb += e2; numb = fmaf(e2, B_[1], numb);
            float e3 = EXP2F(qb * B_[2]); denb += e3; numb = fmaf(e3, B_[3], numb);
        }
        float oa = numa / dena, ob = numb / denb;
        o_l[ra_ * 64 + lane] = f2bf(oa);
        o_l[rb_ * 64 + lane] = f2bf(ob);

        // out-proj (wo from global/L1) + bias + residual
        float res_a = t_lds[ta * 66 + lane];
        float res_b = t_lds[tb * 66 + lane];
        float oa2 = bo_c, ob2 = bo_c;
        #pragma unroll
        for (int dp4 = 0; dp4 < 8; ++dp4) {
            u32x4 pw  = *(const u32x4*)&wop[lane * 32 + ((dp4 ^ c7) << 2)];
            u32x4 opa = *(const u32x4*)&o_l[ra_ * 64 + dp4 * 8];  // uniform bcast
            u32x4 opb = *(const u32x4*)&o_l[rb_ * 64 + dp4 * 8];
            #pragma unroll
            for (int j = 0; j < 4; ++j) {
                oa2 = dot2bf(pw[j], opa[j], oa2);
                ob2 = dot2bf(pw[j], opb[j], ob2);
            }
        }
        t_lds[ta * 66 + lane] = oa2 + res_a;
        t_lds[tb * 66 + lane] = ob2 + res_b;
    }
    __syncthreads();

    // ---- store: 4 floats/thread, float4, coalesced 64B groups ----
    {
        int c = tid >> 2, xg = tid & 3;
        f32x4 o4;
        #pragma unroll
        for (int j = 0; j < 4; ++j) o4[j] = t_lds[(xg * 4 + j) * 66 + c];
        *(f32x4*)&out[((b * 64 + c) * 64 + y) * 64 + x0 + xg * 4] = o4;
    }
}

extern "C" void kernel_launch(void* const* d_in, const int* in_sizes, int n_in,
                              void* d_out, int out_size, void* d_ws, size_t ws_size,
                              hipStream_t stream) {
    const float* x  = (const float*)d_in[0];
    const float* w1 = (const float*)d_in[1];
    const float* b1 = (const float*)d_in[2];
    const float* w2 = (const float*)d_in[3];
    const float* b2 = (const float*)d_in[4];
    const float* wq = (const float*)d_in[5];
    const float* wk = (const float*)d_in[6];
    const float* wv = (const float*)d_in[7];
    const float* wo = (const float*)d_in[8];
    const float* bo = (const float*)d_in[9];
    float* out = (float*)d_out;

    // ws: wp uint[8192] (32 KB) | wt1 bf16[36864] | wt2 bf16[36864]
    unsigned*       wpp = (unsigned*)d_ws;
    unsigned short* wt1 = (unsigned short*)((char*)d_ws + 32768);
    unsigned short* wt2 = wt1 + 36864;

    prep_w<<<320, 256, 0, stream>>>(w1, w2, wq, wk, wv, wo, wt1, wt2, wpp);
    fused_k<<<512, 256, 0, stream>>>(x, wt1, wt2, b1, b2, wpp, bo, out);
}

// Round 5
// 94.790 us; speedup vs baseline: 3.8140x; 1.0220x over previous
//
#include <hip/hip_runtime.h>
#include <hip/hip_bf16.h>

// ---------------------------------------------------------------------------
// B=2, L=64, H=W=64. Fully fused, 2 dispatches:
//   prep_w: repack conv weights into lane-coalesced MFMA A-fragment order,
//           attn weights into dp4-major bf16-pair order (both -> ws).
//   fused_k: block (b,y,16-strip): conv1 (flat-N MFMA) -> r1(LDS bf16) ->
//            conv2 (MFMA) -> h(LDS) -> rank-1 attention + out-proj + residual.
//   All global weight reads are lane-coalesced 16B/lane (1KB/instr).
// ---------------------------------------------------------------------------

#define IMG 262144

using frag_ab = __attribute__((ext_vector_type(8))) short;  // 8 bf16
using frag_cd = __attribute__((ext_vector_type(4))) float;  // 4 fp32
typedef unsigned u32x4 __attribute__((ext_vector_type(4)));
typedef float    f32x2 __attribute__((ext_vector_type(2)));
typedef float    f32x4 __attribute__((ext_vector_type(4)));

static __device__ inline unsigned short f2bf(float f) {
    unsigned u = __float_as_uint(f);
    return (unsigned short)((u + 0x7FFFu + ((u >> 16) & 1u)) >> 16);
}
static __device__ inline float bflo(unsigned p) { return __uint_as_float(p << 16); }
static __device__ inline float bfhi(unsigned p) { return __uint_as_float(p & 0xFFFF0000u); }

#if __has_builtin(__builtin_amdgcn_fdot2_f32_bf16)
typedef __bf16 bf16x2 __attribute__((ext_vector_type(2)));
static __device__ inline float dot2bf(unsigned a, unsigned b, float c) {
    union U { unsigned u; bf16x2 v; };
    U ua, ub; ua.u = a; ub.u = b;
    return __builtin_amdgcn_fdot2_f32_bf16(ua.v, ub.v, c, false);
}
#else
static __device__ inline float dot2bf(unsigned a, unsigned b, float c) {
    return fmaf(bflo(a), bflo(b), fmaf(bfhi(a), bfhi(b), c));
}
#endif

#if __has_builtin(__builtin_amdgcn_exp2f)
#define EXP2F(x) __builtin_amdgcn_exp2f(x)
#else
#define EXP2F(x) __expf(0.6931471805599453f * (x))
#endif

// ---------------- prep -----------------------------------------------------
// Conv: wt[((t*4+g)*2+s)*64 + lane]*8 chunk holds w[oc=16g+m][ic=32s+8q+e]
//       where lane = q*16+m  -> fused A-frag load is lane-coalesced b128.
// Attn: wp[((mat*8+dp4)*64 + c)*4 + j] = pack(w[c][2(4dp4+j)], w[c][2(4dp4+j)+1])
//       -> fused u32x4 read at lane=c is lane-coalesced (16B stride).
__global__ __launch_bounds__(256) void prep_w(
    const float* __restrict__ w1, const float* __restrict__ w2,
    const float* __restrict__ wq, const float* __restrict__ wk,
    const float* __restrict__ wv, const float* __restrict__ wo,
    unsigned short* __restrict__ wt1, unsigned short* __restrict__ wt2,
    unsigned* __restrict__ wp)
{
    int i = blockIdx.x * 256 + threadIdx.x;
    if (i < 73728) {
        int mat = i >= 36864;
        int j = i - mat * 36864;
        int tap = j >> 12;
        int oc  = (j >> 6) & 63;
        int ic  = j & 63;
        const float* w = mat ? w2 : w1;
        int g = oc >> 4, m = oc & 15;
        int s = ic >> 5, q = (ic >> 3) & 3, e = ic & 7;
        int dst = ((((tap * 4 + g) * 2 + s) * 4 + q) * 16 + m) * 8 + e;
        (mat ? wt2 : wt1)[dst] = f2bf(w[(oc * 64 + ic) * 9 + tap]);
    } else {
        int a = i - 73728;               // 0..8191
        int mat = a >> 11;
        int r = a & 2047;
        int c = r >> 5, dp = r & 31;
        const float* w = (mat == 0) ? wq : (mat == 1) ? wk : (mat == 2) ? wv : wo;
        unsigned val = (unsigned)f2bf(w[c * 64 + 2 * dp]) |
                       ((unsigned)f2bf(w[c * 64 + 2 * dp + 1]) << 16);
        wp[((mat * 8 + (dp >> 2)) * 64 + c) * 4 + (dp & 3)] = val;
    }
}

// ---------------- fully fused kernel ---------------------------------------
// Grid 512 = 2 b x 64 y x 4 xstrips(16). 4 waves; wave w owns oc [16w,16w+16)
// in conv phases and tokens [4w,4w+4) in attention. 3 blocks/CU.
__global__ __launch_bounds__(256, 3) void fused_k(
    const float* __restrict__ x,
    const unsigned short* __restrict__ wt1, const unsigned short* __restrict__ wt2,
    const float* __restrict__ b1, const float* __restrict__ b2,
    const unsigned* __restrict__ wp, const float* __restrict__ bo,
    float* __restrict__ out)
{
    __shared__ __align__(16) unsigned short xt[5 * 20 * 72];    // 14400 B
    __shared__ __align__(16) unsigned short r1[54 * 72];        //  7776 B
    __shared__ __align__(16) float          t_lds[16 * 66];     //  4224 B
    __shared__ __align__(16) unsigned       tp[16 * 32];        //  2048 B
    __shared__ __align__(16) f32x2          kv[16 * 64];        //  8192 B
    __shared__ __align__(16) unsigned short o_l[16 * 64];       //  2048 B

    const int tid  = threadIdx.x;
    const int b    = blockIdx.x >> 8;
    const int y    = (blockIdx.x >> 2) & 63;
    const int x0   = (blockIdx.x & 3) * 16;
    const int wv_  = tid >> 6;
    const int lane = tid & 63;
    const int m    = lane & 15;
    const int q    = lane >> 4;
    const int oc0  = wv_ * 16;

    // ---- A1 fragments: lane-coalesced 1KB loads ----
    frag_ab A1[9][2];
    #pragma unroll
    for (int t = 0; t < 9; ++t)
        #pragma unroll
        for (int s = 0; s < 2; ++s)
            A1[t][s] = *(const frag_ab*)&wt1[(((t * 4 + wv_) * 2 + s) * 64 + lane) * 8];

    // ---- stage x tile: rows y-2..y+2, xslots 0..19 (gx = x0-2+xslot) ----
    {
        const int xl  = tid & 15;
        const int sub = tid >> 4;
        #pragma unroll
        for (int i = 0; i < 20; ++i) {
            int pair = i * 16 + sub;          // 0..319
            int row = pair >> 6, ic = pair & 63;
            int yy = y - 2 + row;
            int yc = min(max(yy, 0), 63);
            float f = x[((b * 64 + ic) * 64 + yc) * 64 + x0 + xl];
            unsigned short v = f2bf(f);
            if (yy != yc) v = 0;
            xt[(row * 20 + xl + 2) * 72 + ic] = v;
        }
        #pragma unroll
        for (int j = 0; j < 5; ++j) {         // halo columns xslot {0,1,18,19}
            int e = j * 256 + tid;            // 0..1279
            int col = e & 3, pair = e >> 2;
            int row = pair >> 6, ic = pair & 63;
            int xsl = (col < 2) ? col : col + 16;
            int gx = x0 - 2 + xsl;
            int gxc = min(max(gx, 0), 63);
            int yy = y - 2 + row;
            int yc = min(max(yy, 0), 63);
            float f = x[((b * 64 + ic) * 64 + yc) * 64 + gxc];
            unsigned short v = f2bf(f);
            if (yy != yc || gx != gxc) v = 0;
            xt[(row * 20 + xsl) * 72 + ic] = v;
        }
    }
    __syncthreads();

    // ---- conv1: flat N = (row 0..2) x (xs 0..17) = 54, 4 tiles of 16 ----
    int pb[4], rn_[4], xs_[4];
    bool nv[4];
    #pragma unroll
    for (int nt = 0; nt < 4; ++nt) {
        int n  = nt * 16 + m;
        int nc = min(n, 53);
        int rr = nc / 18, xx = nc - rr * 18;
        rn_[nt] = rr; xs_[nt] = xx; nv[nt] = (n < 54);
        pb[nt] = (rr * 20 + xx) * 72 + q * 8;
    }
    frag_cd acc1[4];
    #pragma unroll
    for (int i = 0; i < 4; ++i) acc1[i] = (frag_cd){0.f, 0.f, 0.f, 0.f};

    #pragma unroll
    for (int ky = 0; ky < 3; ++ky)
        #pragma unroll
        for (int kx = 0; kx < 3; ++kx)
            #pragma unroll
            for (int s = 0; s < 2; ++s) {
                frag_ab a = A1[ky * 3 + kx][s];
                int off = (ky * 20 + kx) * 72 + s * 32;
                #pragma unroll
                for (int nt = 0; nt < 4; ++nt)
                    acc1[nt] = __builtin_amdgcn_mfma_f32_16x16x32_bf16(
                        a, *(const frag_ab*)&xt[pb[nt] + off], acc1[nt], 0, 0, 0);
            }

    // ---- A2 fragments (loaded now: latency overlaps epilogue + barrier) ----
    frag_ab A2[9][2];
    #pragma unroll
    for (int t = 0; t < 9; ++t)
        #pragma unroll
        for (int s = 0; s < 2; ++s)
            A2[t][s] = *(const frag_ab*)&wt2[(((t * 4 + wv_) * 2 + s) * 64 + lane) * 8];

    // ---- r1 = bf16(relu(conv1+b1)), zero at image edges ----
    {
        frag_cd b1f = *(const frag_cd*)&b1[oc0 + q * 4];
        #pragma unroll
        for (int nt = 0; nt < 4; ++nt) {
            if (!nv[nt]) continue;
            int n = nt * 16 + m;
            int gy = y - 1 + rn_[nt];
            int gx = x0 - 1 + xs_[nt];
            bool oob = (gy < 0) | (gy > 63) | (gx < 0) | (gx > 63);
            #pragma unroll
            for (int r = 0; r < 4; ++r) {
                float v = fmaxf(acc1[nt][r] + b1f[r], 0.f);
                r1[n * 72 + oc0 + q * 4 + r] = oob ? (unsigned short)0 : f2bf(v);
            }
        }
    }
    __syncthreads();

    // ---- conv2: 1 N-tile (16 tokens), 18 MFMA/wave ----
    frag_cd acc2 = (frag_cd){0.f, 0.f, 0.f, 0.f};
    #pragma unroll
    for (int ky = 0; ky < 3; ++ky)
        #pragma unroll
        for (int kx = 0; kx < 3; ++kx)
            #pragma unroll
            for (int s = 0; s < 2; ++s)
                acc2 = __builtin_amdgcn_mfma_f32_16x16x32_bf16(
                    A2[ky * 3 + kx][s],
                    *(const frag_ab*)&r1[(ky * 18 + m + kx) * 72 + s * 32 + q * 8],
                    acc2, 0, 0, 0);

    // ---- h -> t_lds (fp32 residual) + tp (bf16 pairs) ----
    {
        frag_cd b2f = *(const frag_cd*)&b2[oc0 + q * 4];
        float hv[4];
        #pragma unroll
        for (int r = 0; r < 4; ++r) {
            hv[r] = acc2[r] + b2f[r];
            t_lds[m * 66 + oc0 + q * 4 + r] = hv[r];
        }
        int dpb = (oc0 >> 1) + q * 2;
        tp[m * 32 + dpb + 0] = (unsigned)f2bf(hv[0]) | ((unsigned)f2bf(hv[1]) << 16);
        tp[m * 32 + dpb + 1] = (unsigned)f2bf(hv[2]) | ((unsigned)f2bf(hv[3]) << 16);
    }
    __syncthreads();

    // ---- attention: wave handles its 4 tokens in one pass ----
    const float bo_c = bo[lane];
    const int t0_ = wv_ * 4;

    // q,k,v matvecs (lane = output channel); weights global, lane-coalesced
    float qq[4] = {0,0,0,0}, kk[4] = {0,0,0,0}, vv[4] = {0,0,0,0};
    #pragma unroll
    for (int dp4 = 0; dp4 < 8; ++dp4) {
        u32x4 pq = *(const u32x4*)&wp[(dp4 * 64 + lane) * 4];
        u32x4 pk = *(const u32x4*)&wp[((8 + dp4) * 64 + lane) * 4];
        u32x4 pv = *(const u32x4*)&wp[((16 + dp4) * 64 + lane) * 4];
        #pragma unroll
        for (int i = 0; i < 4; ++i) {
            u32x4 tpv = *(const u32x4*)&tp[(t0_ + i) * 32 + dp4 * 4];  // bcast
            #pragma unroll
            for (int j = 0; j < 4; ++j) {
                qq[i] = dot2bf(pq[j], tpv[j], qq[i]);
                kk[i] = dot2bf(pk[j], tpv[j], kk[i]);
                vv[i] = dot2bf(pv[j], tpv[j], vv[i]);
            }
        }
    }

    // L2 norms (wave butterfly); q pre-scaled by log2e for exp2
    float nq[4], nk[4];
    #pragma unroll
    for (int i = 0; i < 4; ++i) { nq[i] = qq[i] * qq[i]; nk[i] = kk[i] * kk[i]; }
    #pragma unroll
    for (int s = 32; s > 0; s >>= 1)
        #pragma unroll
        for (int i = 0; i < 4; ++i) {
            nq[i] += __shfl_xor(nq[i], s);
            nk[i] += __shfl_xor(nk[i], s);
        }
    #pragma unroll
    for (int i = 0; i < 4; ++i) {
        qq[i] = qq[i] / fmaxf(sqrtf(nq[i]), 1e-12f) * 1.44269504f;
        kk[i] = kk[i] / fmaxf(sqrtf(nk[i]), 1e-12f);
        kv[(t0_ + i) * 64 + lane] = (f32x2){kk[i], vv[i]};
    }

    // softmax: scores in [-1,1] -> no max subtraction
    float den[4] = {0,0,0,0}, num[4] = {0,0,0,0};
    #pragma unroll 4
    for (int d2 = 0; d2 < 32; ++d2) {
        #pragma unroll
        for (int i = 0; i < 4; ++i) {
            f32x4 K = *(const f32x4*)&kv[(t0_ + i) * 64 + d2 * 2];  // k0,v0,k1,v1
            float e0 = EXP2F(qq[i] * K[0]); den[i] += e0; num[i] = fmaf(e0, K[1], num[i]);
            float e1 = EXP2F(qq[i] * K[2]); den[i] += e1; num[i] = fmaf(e1, K[3], num[i]);
        }
    }
    #pragma unroll
    for (int i = 0; i < 4; ++i)
        o_l[(t0_ + i) * 64 + lane] = f2bf(num[i] / den[i]);

    // out-proj + bias + residual (wo global, lane-coalesced)
    float res[4], po[4];
    #pragma unroll
    for (int i = 0; i < 4; ++i) {
        res[i] = t_lds[(t0_ + i) * 66 + lane];
        po[i]  = bo_c;
    }
    #pragma unroll
    for (int dp4 = 0; dp4 < 8; ++dp4) {
        u32x4 pw = *(const u32x4*)&wp[((24 + dp4) * 64 + lane) * 4];
        #pragma unroll
        for (int i = 0; i < 4; ++i) {
            u32x4 ov = *(const u32x4*)&o_l[(t0_ + i) * 64 + dp4 * 8];  // bcast
            #pragma unroll
            for (int j = 0; j < 4; ++j)
                po[i] = dot2bf(pw[j], ov[j], po[i]);
        }
    }
    #pragma unroll
    for (int i = 0; i < 4; ++i)
        t_lds[(t0_ + i) * 66 + lane] = po[i] + res[i];
    __syncthreads();

    // ---- store: 4 floats/thread, float4, coalesced ----
    {
        int c = tid >> 2, xg = tid & 3;
        f32x4 o4;
        #pragma unroll
        for (int j = 0; j < 4; ++j) o4[j] = t_lds[(xg * 4 + j) * 66 + c];
        *(f32x4*)&out[((b * 64 + c) * 64 + y) * 64 + x0 + xg * 4] = o4;
    }
}

extern "C" void kernel_launch(void* const* d_in, const int* in_sizes, int n_in,
                              void* d_out, int out_size, void* d_ws, size_t ws_size,
                              hipStream_t stream) {
    const float* x  = (const float*)d_in[0];
    const float* w1 = (const float*)d_in[1];
    const float* b1 = (const float*)d_in[2];
    const float* w2 = (const float*)d_in[3];
    const float* b2 = (const float*)d_in[4];
    const float* wq = (const float*)d_in[5];
    const float* wk = (const float*)d_in[6];
    const float* wv = (const float*)d_in[7];
    const float* wo = (const float*)d_in[8];
    const float* bo = (const float*)d_in[9];
    float* out = (float*)d_out;

    // ws: wp uint[8192] (32 KB) | wt1 bf16[36864] | wt2 bf16[36864]
    unsigned*       wpp = (unsigned*)d_ws;
    unsigned short* wt1 = (unsigned short*)((char*)d_ws + 32768);
    unsigned short* wt2 = wt1 + 36864;

    prep_w<<<320, 256, 0, stream>>>(w1, w2, wq, wk, wv, wo, wt1, wt2, wpp);
    fused_k<<<512, 256, 0, stream>>>(x, wt1, wt2, b1, b2, wpp, bo, out);
}

// Round 6
// 88.193 us; speedup vs baseline: 4.0992x; 1.0748x over previous
//
#include <hip/hip_runtime.h>
#include <hip/hip_bf16.h>

// ---------------------------------------------------------------------------
// B=2, L=64, H=W=64. Fully fused, 2 dispatches.
//   prep_w: conv + attn weights -> bf16 MFMA A-fragment layouts (ws).
//   fused_k: block (b,y,16-strip): conv1 (flat-N MFMA) -> r1(LDS bf16) ->
//            conv2 (MFMA) -> h(LDS) -> qkv via MFMA -> l2norm (cross-wave) ->
//            softmax (VALU exp2) -> out-proj via MFMA -> +bias+residual ->
//            global store straight from MFMA-D layout.
// ---------------------------------------------------------------------------

#define IMG 262144

using frag_ab = __attribute__((ext_vector_type(8))) short;  // 8 bf16
using frag_cd = __attribute__((ext_vector_type(4))) float;  // 4 fp32
typedef unsigned u32x4 __attribute__((ext_vector_type(4)));
typedef float    f32x2 __attribute__((ext_vector_type(2)));
typedef float    f32x4 __attribute__((ext_vector_type(4)));

static __device__ inline unsigned short f2bf(float f) {
    unsigned u = __float_as_uint(f);
    return (unsigned short)((u + 0x7FFFu + ((u >> 16) & 1u)) >> 16);
}
static __device__ inline unsigned packbf(float a, float b) {
    return (unsigned)f2bf(a) | ((unsigned)f2bf(b) << 16);
}

#if __has_builtin(__builtin_amdgcn_exp2f)
#define EXP2F(x) __builtin_amdgcn_exp2f(x)
#else
#define EXP2F(x) __expf(0.6931471805599453f * (x))
#endif

// ---------------- prep -----------------------------------------------------
// Conv (unchanged): wt[((t*4+g)*2+s)*64 + lane]*8 holds w[oc=16g+m][ic=32s+8q+e],
//   lane = q*16+m  -> A-frag load is lane-coalesced b128.
// Attn: wa[mat*4096 + ((g*2+s)*64 + lane)*8 + e] = w[oc=16g+m][ic=32s+8q+e]
//   (same A-frag layout, mat in {q,k,v,o}).
__global__ __launch_bounds__(256) void prep_w(
    const float* __restrict__ w1, const float* __restrict__ w2,
    const float* __restrict__ wq, const float* __restrict__ wk,
    const float* __restrict__ wv, const float* __restrict__ wo,
    unsigned short* __restrict__ wt1, unsigned short* __restrict__ wt2,
    unsigned short* __restrict__ wa)
{
    int i = blockIdx.x * 256 + threadIdx.x;      // 0..90111
    if (i < 73728) {
        int mat = i >= 36864;
        int j = i - mat * 36864;
        int tap = j >> 12;
        int oc  = (j >> 6) & 63;
        int ic  = j & 63;
        const float* w = mat ? w2 : w1;
        int g = oc >> 4, mm = oc & 15;
        int s = ic >> 5, qq = (ic >> 3) & 3, e = ic & 7;
        int dst = ((((tap * 4 + g) * 2 + s) * 4 + qq) * 16 + mm) * 8 + e;
        (mat ? wt2 : wt1)[dst] = f2bf(w[(oc * 64 + ic) * 9 + tap]);
    } else {
        int a = i - 73728;                        // 0..16383
        int mat = a >> 12;
        int j = a & 4095;
        int e    = j & 7;
        int lane = (j >> 3) & 63;
        int gs   = j >> 9;                        // 0..7
        int g = gs >> 1, s = gs & 1;
        int qq = lane >> 4, mm = lane & 15;
        int oc = 16 * g + mm;
        int ic = 32 * s + 8 * qq + e;
        const float* w = (mat == 0) ? wq : (mat == 1) ? wk : (mat == 2) ? wv : wo;
        wa[mat * 4096 + j] = f2bf(w[oc * 64 + ic]);
    }
}

// ---------------- fully fused kernel ---------------------------------------
// Grid 512 = 2 b x 64 y x 4 xstrips(16). 4 waves; wave w owns channel slice
// [16w,16w+16) in ALL matmul phases (conv1/conv2/qkv/out-proj).
__global__ __launch_bounds__(256, 2) void fused_k(
    const float* __restrict__ x,
    const unsigned short* __restrict__ wt1, const unsigned short* __restrict__ wt2,
    const float* __restrict__ b1, const float* __restrict__ b2,
    const unsigned short* __restrict__ wa, const float* __restrict__ bo,
    float* __restrict__ out)
{
    __shared__ __align__(16) unsigned short xt[5 * 20 * 72];  // 14400 B
    __shared__ __align__(16) unsigned short r1[54 * 72];      //  7776 B
    __shared__ __align__(16) float          t_lds[16 * 68];   //  4352 B (h fp32)
    __shared__ __align__(16) unsigned       tp[16 * 36];      //  2304 B (h bf16 pairs)
    __shared__ __align__(16) f32x2          kv[16 * 66];      //  8448 B
    __shared__ __align__(16) unsigned       o_l32[16 * 36];   //  2304 B
    __shared__ __align__(16) f32x2          nrm[4 * 17];      //   544 B

    const int tid  = threadIdx.x;
    const int b    = blockIdx.x >> 8;
    const int y    = (blockIdx.x >> 2) & 63;
    const int x0   = (blockIdx.x & 3) * 16;
    const int wv_  = tid >> 6;
    const int lane = tid & 63;
    const int m    = lane & 15;
    const int qd   = lane >> 4;
    const int oc0  = wv_ * 16;

    // ---- A1 fragments: lane-coalesced 1KB loads ----
    frag_ab A1[9][2];
    #pragma unroll
    for (int t = 0; t < 9; ++t)
        #pragma unroll
        for (int s = 0; s < 2; ++s)
            A1[t][s] = *(const frag_ab*)&wt1[(((t * 4 + wv_) * 2 + s) * 64 + lane) * 8];

    // ---- stage x tile rows y-2..y+2, xslots 0..19 (gx = x0-2+xsl) ----
    // float4 coalesced loads, branch-free clamp; OOB columns forced to 0.
    #pragma unroll
    for (int it = 0; it < 10; ++it) {
        int e    = it * 256 + tid;        // 0..2559
        int grp  = e & 7;
        int pair = e >> 3;                // 0..319
        int row = pair >> 6, ic = pair & 63;
        int yy = y - 2 + row;
        int yc = min(max(yy, 0), 63);
        int gx0 = x0 - 8 + grp * 4;
        int gxl = min(max(gx0, 0), 60);
        f32x4 v = *(const f32x4*)&x[((b * 64 + ic) * 64 + yc) * 64 + gxl];
        #pragma unroll
        for (int j = 0; j < 4; ++j) {
            int gx  = gx0 + j;
            int xsl = gx - x0 + 2;
            if (xsl < 0 || xsl >= 20) continue;
            unsigned short val =
                (yy == yc && gx >= 0 && gx <= 63) ? f2bf(v[j]) : (unsigned short)0;
            xt[(row * 20 + xsl) * 72 + ic] = val;
        }
    }
    __syncthreads();

    // ---- conv1: flat N = (row 0..2) x (xs 0..17) = 54, 4 tiles of 16 ----
    int pb[4], rn_[4], xs_[4];
    bool nv[4];
    #pragma unroll
    for (int nt = 0; nt < 4; ++nt) {
        int n  = nt * 16 + m;
        int nc = min(n, 53);
        int rr = nc / 18, xx = nc - rr * 18;
        rn_[nt] = rr; xs_[nt] = xx; nv[nt] = (n < 54);
        pb[nt] = (rr * 20 + xx) * 72 + qd * 8;
    }
    frag_cd acc1[4];
    #pragma unroll
    for (int i = 0; i < 4; ++i) acc1[i] = (frag_cd){0.f, 0.f, 0.f, 0.f};

    #pragma unroll
    for (int ky = 0; ky < 3; ++ky)
        #pragma unroll
        for (int kx = 0; kx < 3; ++kx)
            #pragma unroll
            for (int s = 0; s < 2; ++s) {
                frag_ab a = A1[ky * 3 + kx][s];
                int off = (ky * 20 + kx) * 72 + s * 32;
                #pragma unroll
                for (int nt = 0; nt < 4; ++nt)
                    acc1[nt] = __builtin_amdgcn_mfma_f32_16x16x32_bf16(
                        a, *(const frag_ab*)&xt[pb[nt] + off], acc1[nt], 0, 0, 0);
            }

    // ---- A2 + attn A-fragments (latency overlaps epilogue + barrier) ----
    frag_ab A2[9][2];
    #pragma unroll
    for (int t = 0; t < 9; ++t)
        #pragma unroll
        for (int s = 0; s < 2; ++s)
            A2[t][s] = *(const frag_ab*)&wt2[(((t * 4 + wv_) * 2 + s) * 64 + lane) * 8];
    frag_ab Aq[2], Ak[2], Av[2], Ao[2];
    #pragma unroll
    for (int s = 0; s < 2; ++s) {
        int off = ((wv_ * 2 + s) * 64 + lane) * 8;
        Aq[s] = *(const frag_ab*)&wa[off];
        Ak[s] = *(const frag_ab*)&wa[4096 + off];
        Av[s] = *(const frag_ab*)&wa[8192 + off];
        Ao[s] = *(const frag_ab*)&wa[12288 + off];
    }

    // ---- r1 = bf16(relu(conv1+b1)), zero at image edges ----
    {
        frag_cd b1f = *(const frag_cd*)&b1[oc0 + qd * 4];
        #pragma unroll
        for (int nt = 0; nt < 4; ++nt) {
            if (!nv[nt]) continue;
            int n = nt * 16 + m;
            int gy = y - 1 + rn_[nt];
            int gx = x0 - 1 + xs_[nt];
            bool oob = (gy < 0) | (gy > 63) | (gx < 0) | (gx > 63);
            #pragma unroll
            for (int r = 0; r < 4; ++r) {
                float v = fmaxf(acc1[nt][r] + b1f[r], 0.f);
                r1[n * 72 + oc0 + qd * 4 + r] = oob ? (unsigned short)0 : f2bf(v);
            }
        }
    }
    __syncthreads();

    // ---- conv2: 1 N-tile (16 tokens), 18 MFMA/wave ----
    frag_cd acc2 = (frag_cd){0.f, 0.f, 0.f, 0.f};
    #pragma unroll
    for (int ky = 0; ky < 3; ++ky)
        #pragma unroll
        for (int kx = 0; kx < 3; ++kx)
            #pragma unroll
            for (int s = 0; s < 2; ++s)
                acc2 = __builtin_amdgcn_mfma_f32_16x16x32_bf16(
                    A2[ky * 3 + kx][s],
                    *(const frag_ab*)&r1[(ky * 18 + m + kx) * 72 + s * 32 + qd * 8],
                    acc2, 0, 0, 0);

    // ---- h -> t_lds (fp32 residual) + tp (bf16 pairs, stride 36) ----
    {
        frag_cd b2f = *(const frag_cd*)&b2[oc0 + qd * 4];
        f32x4 hv;
        #pragma unroll
        for (int r = 0; r < 4; ++r) hv[r] = acc2[r] + b2f[r];
        *(f32x4*)&t_lds[m * 68 + oc0 + qd * 4] = hv;
        int dpb = m * 36 + (oc0 >> 1) + qd * 2;
        tp[dpb + 0] = packbf(hv[0], hv[1]);
        tp[dpb + 1] = packbf(hv[2], hv[3]);
    }
    __syncthreads();

    // ---- qkv via MFMA: wave w -> channels [16w,16w+16) x 16 tokens ----
    frag_cd qA = (frag_cd){0,0,0,0}, kA = (frag_cd){0,0,0,0}, vA = (frag_cd){0,0,0,0};
    #pragma unroll
    for (int s = 0; s < 2; ++s) {
        frag_ab hfrag = *(const frag_ab*)&tp[m * 36 + s * 16 + qd * 4];
        qA = __builtin_amdgcn_mfma_f32_16x16x32_bf16(Aq[s], hfrag, qA, 0, 0, 0);
        kA = __builtin_amdgcn_mfma_f32_16x16x32_bf16(Ak[s], hfrag, kA, 0, 0, 0);
        vA = __builtin_amdgcn_mfma_f32_16x16x32_bf16(Av[s], hfrag, vA, 0, 0, 0);
    }
    // D layout: lane(qd,m) reg r = {q,k,v}[ch=16w+4qd+r][tok=m]

    // ---- L2 norms: intra-wave (over qd) then cross-wave via LDS ----
    float nq = qA[0]*qA[0] + qA[1]*qA[1] + qA[2]*qA[2] + qA[3]*qA[3];
    float nk = kA[0]*kA[0] + kA[1]*kA[1] + kA[2]*kA[2] + kA[3]*kA[3];
    nq += __shfl_xor(nq, 16); nq += __shfl_xor(nq, 32);
    nk += __shfl_xor(nk, 16); nk += __shfl_xor(nk, 32);
    if (qd == 0) nrm[wv_ * 17 + m] = (f32x2){nq, nk};
    __syncthreads();
    f32x2 p0 = nrm[m],      p1 = nrm[17 + m];
    f32x2 p2 = nrm[34 + m], p3 = nrm[51 + m];
    float snq = p0.x + p1.x + p2.x + p3.x;
    float snk = p0.y + p1.y + p2.y + p3.y;
    float rq = 1.4426950408889634f / fmaxf(sqrtf(snq), 1e-12f);
    float rk = 1.0f / fmaxf(sqrtf(snk), 1e-12f);

    // normalized q stays in regs; k,v -> kv[tok][d]
    float qn[4];
    #pragma unroll
    for (int r = 0; r < 4; ++r) {
        qn[r] = qA[r] * rq;
        kv[m * 66 + oc0 + qd * 4 + r] = (f32x2){kA[r] * rk, vA[r]};
    }
    __syncthreads();

    // ---- softmax: scores in [-1,1], no max subtraction ----
    float den[4] = {0, 0, 0, 0}, num[4] = {0, 0, 0, 0};
    #pragma unroll 8
    for (int d2 = 0; d2 < 32; ++d2) {
        f32x4 K = *(const f32x4*)&kv[m * 66 + d2 * 2];   // k0,v0,k1,v1
        #pragma unroll
        for (int r = 0; r < 4; ++r) {
            float e0 = EXP2F(qn[r] * K[0]); den[r] += e0; num[r] = fmaf(e0, K[1], num[r]);
            float e1 = EXP2F(qn[r] * K[2]); den[r] += e1; num[r] = fmaf(e1, K[3], num[r]);
        }
    }
    {
        int ob = m * 36 + wv_ * 8 + qd * 2;
        o_l32[ob + 0] = packbf(num[0] / den[0], num[1] / den[1]);
        o_l32[ob + 1] = packbf(num[2] / den[2], num[3] / den[3]);
    }
    __syncthreads();

    // ---- out-proj via MFMA + bias + residual -> global ----
    frag_cd oA = (frag_cd){0, 0, 0, 0};
    #pragma unroll
    for (int s = 0; s < 2; ++s)
        oA = __builtin_amdgcn_mfma_f32_16x16x32_bf16(
            Ao[s], *(const frag_ab*)&o_l32[m * 36 + s * 16 + qd * 4], oA, 0, 0, 0);

    f32x4 bo4 = *(const f32x4*)&bo[oc0 + qd * 4];
    f32x4 res = *(const f32x4*)&t_lds[m * 68 + oc0 + qd * 4];
    #pragma unroll
    for (int r = 0; r < 4; ++r) {
        float v = oA[r] + bo4[r] + res[r];
        out[((b * 64 + oc0 + qd * 4 + r) * 64 + y) * 64 + x0 + m] = v;
    }
}

extern "C" void kernel_launch(void* const* d_in, const int* in_sizes, int n_in,
                              void* d_out, int out_size, void* d_ws, size_t ws_size,
                              hipStream_t stream) {
    const float* x  = (const float*)d_in[0];
    const float* w1 = (const float*)d_in[1];
    const float* b1 = (const float*)d_in[2];
    const float* w2 = (const float*)d_in[3];
    const float* b2 = (const float*)d_in[4];
    const float* wq = (const float*)d_in[5];
    const float* wk = (const float*)d_in[6];
    const float* wv = (const float*)d_in[7];
    const float* wo = (const float*)d_in[8];
    const float* bo = (const float*)d_in[9];
    float* out = (float*)d_out;

    // ws: wa bf16[16384] (32 KB) | wt1 bf16[36864] | wt2 bf16[36864]
    unsigned short* wa  = (unsigned short*)d_ws;
    unsigned short* wt1 = (unsigned short*)((char*)d_ws + 32768);
    unsigned short* wt2 = wt1 + 36864;

    prep_w<<<352, 256, 0, stream>>>(w1, w2, wq, wk, wv, wo, wt1, wt2, wa);
    fused_k<<<512, 256, 0, stream>>>(x, wt1, wt2, b1, b2, wa, bo, out);
}